// Round 2
// baseline (335.413 us; speedup 1.0000x reference)
//
#include <hip/hip_runtime.h>

#define B_ 4
#define S_ 2048
#define D_ 768
#define H_ 12
#define HD_ 64
#define T_ (B_ * S_)  // 8192

typedef __bf16 bf16x8 __attribute__((ext_vector_type(8)));
typedef __bf16 bf16x4 __attribute__((ext_vector_type(4)));
typedef float  f32x4  __attribute__((ext_vector_type(4)));

__device__ __forceinline__ f32x4 mfma16(bf16x8 a, bf16x8 b, f32x4 c) {
  return __builtin_amdgcn_mfma_f32_16x16x32_bf16(a, b, c, 0, 0, 0);
}

// async global->LDS, 16B per lane. LDS dest is wave-uniform base + lane*16.
__device__ __forceinline__ void gload16(const __bf16* g, __bf16* lds) {
  __builtin_amdgcn_global_load_lds(
      (__attribute__((address_space(1))) void*)g,
      (__attribute__((address_space(3))) void*)lds, 16, 0, 0);
}

// ---------------- fp32 -> bf16 convert (vectorized, optional scale) ----------
__global__ void cvt_f32_bf16(const float* __restrict__ in, __bf16* __restrict__ out,
                             int n4, float scale) {
  int i = blockIdx.x * blockDim.x + threadIdx.x;
  if (i >= n4) return;
  float4 v = reinterpret_cast<const float4*>(in)[i];
  bf16x4 o;
  o[0] = (__bf16)(v.x * scale);
  o[1] = (__bf16)(v.y * scale);
  o[2] = (__bf16)(v.z * scale);
  o[3] = (__bf16)(v.w * scale);
  reinterpret_cast<bf16x4*>(out)[i] = o;
}

// ---------------- GEMM: C[m][n] = sum_k A[m][k] * W[n][k]  (B^T layout) ------
// MODE 0: fused QKV projection. blockIdx.y in [0,18): mat = y/6 (0=Q,1=K,2=V),
//         n-tile = y%6. Epilogue scatters Q,K -> [B,H,S,64] bf16, V -> [B,H,64,S].
// MODE 1: output projection, fp32 out + bias.
template <int MODE>
__global__ __launch_bounds__(256, 2)
void gemm_bt(const __bf16* __restrict__ A,
             const __bf16* __restrict__ W0, const __bf16* __restrict__ W1,
             const __bf16* __restrict__ W2,
             __bf16* __restrict__ Oq, __bf16* __restrict__ Ok,
             __bf16* __restrict__ Ov,
             float* __restrict__ fout, const float* __restrict__ bias) {
  constexpr int K = D_;  // 768
  __shared__ __align__(16) __bf16 sA[128 * 32];
  __shared__ __align__(16) __bf16 sB[128 * 32];

  const int tid = threadIdx.x;
  const int l = tid & 63;
  const int w = tid >> 6;
  const int m0 = blockIdx.x * 128;

  int mat, n0;
  const __bf16* Wm;
  if (MODE == 0) {
    mat = blockIdx.y / 6;
    n0 = (blockIdx.y % 6) * 128;
    Wm = (mat == 0) ? W0 : (mat == 1) ? W1 : W2;
  } else {
    mat = 0;
    n0 = blockIdx.y * 128;
    Wm = W0;
  }

  const int srow = l >> 2;
  const int sk = (l & 3) * 8;
  const int c0 = w * 2, c1 = w * 2 + 1;
  const __bf16* gA0 = A + (m0 + c0 * 16 + srow) * K + sk;
  const __bf16* gA1 = A + (m0 + c1 * 16 + srow) * K + sk;
  const __bf16* gB0 = Wm + (n0 + c0 * 16 + srow) * K + sk;
  const __bf16* gB1 = Wm + (n0 + c1 * 16 + srow) * K + sk;
  __bf16* lA0 = &sA[c0 * 512];
  __bf16* lA1 = &sA[c1 * 512];
  __bf16* lB0 = &sB[c0 * 512];
  __bf16* lB1 = &sB[c1 * 512];

  f32x4 acc[4][4] = {};
  const int wr = w >> 1, wc = w & 1;
  const int fr = l & 15, fq = l >> 4;

  for (int kt = 0; kt < K / 32; ++kt) {
    const int ko = kt * 32;
    gload16(gA0 + ko, lA0);
    gload16(gA1 + ko, lA1);
    gload16(gB0 + ko, lB0);
    gload16(gB1 + ko, lB1);
    __syncthreads();
    bf16x8 af[4], bfr[4];
#pragma unroll
    for (int mi = 0; mi < 4; ++mi)
      af[mi] = *reinterpret_cast<const bf16x8*>(
          &sA[(wr * 64 + mi * 16 + fr) * 32 + fq * 8]);
#pragma unroll
    for (int ni = 0; ni < 4; ++ni)
      bfr[ni] = *reinterpret_cast<const bf16x8*>(
          &sB[(wc * 64 + ni * 16 + fr) * 32 + fq * 8]);
#pragma unroll
    for (int mi = 0; mi < 4; ++mi)
#pragma unroll
      for (int ni = 0; ni < 4; ++ni)
        acc[mi][ni] = mfma16(af[mi], bfr[ni], acc[mi][ni]);
    __syncthreads();
  }

#pragma unroll
  for (int mi = 0; mi < 4; ++mi) {
    const int mbase = m0 + wr * 64 + mi * 16 + fq * 4;
#pragma unroll
    for (int ni = 0; ni < 4; ++ni) {
      const int o = n0 + wc * 64 + ni * 16 + fr;
#pragma unroll
      for (int r = 0; r < 4; ++r) {
        const float v = acc[mi][ni][r];
        const int mm = mbase + r;
        if (MODE == 1) {
          fout[mm * D_ + o] = v + bias[o];
        } else {
          const int b = mm >> 11, s = mm & (S_ - 1);
          const int h = o >> 6, hd = o & 63;
          if (mat == 0)
            Oq[((size_t)((b * H_ + h) * S_ + s)) * HD_ + hd] = (__bf16)v;
          else if (mat == 1)
            Ok[((size_t)((b * H_ + h) * S_ + s)) * HD_ + hd] = (__bf16)v;
          else
            Ov[((size_t)((b * H_ + h) * HD_ + hd)) * S_ + s] = (__bf16)v;
        }
      }
    }
  }
}

// ---------------- causal flash attention, KV-split within block ---------------
// grid (S/32, B*H), 256 threads. All 4 waves share one 32-row q-tile; wave w
// processes KV tiles t = w, w+4, ... (KVBLK=64). Online-softmax partials
// (m, l, acc) are combined across waves through LDS at the end.
__global__ __launch_bounds__(256, 3)
void attn_kernel(const __bf16* __restrict__ Q, const __bf16* __restrict__ Kt,
                 const __bf16* __restrict__ Vt, __bf16* __restrict__ C) {
  // per-wave region: 32*66 f32 combine buffer; first 4 KB doubles as the
  // bf16 [32][64] P-staging tile (XOR-swizzled) during the main loop.
  __shared__ __align__(16) float sAccF[4 * 32 * 66];
  __shared__ float sM[4][32];
  __shared__ float sL[4][32];

  const int tid = threadIdx.x;
  const int l = tid & 63;
  const int w = tid >> 6;
  const int fr = l & 15, fq = l >> 4;
  const int bh = blockIdx.y;
  const int qb = blockIdx.x * 32;

  const __bf16* qh = Q + (size_t)bh * S_ * HD_;
  const __bf16* kh = Kt + (size_t)bh * S_ * HD_;
  const __bf16* vh = Vt + (size_t)bh * HD_ * S_;

  float* accw = &sAccF[w * (32 * 66)];
  char* sPb = reinterpret_cast<char*>(accw);  // bf16 [32][64], swizzled

  bf16x8 qf[2][2];
#pragma unroll
  for (int mi = 0; mi < 2; ++mi)
#pragma unroll
    for (int ks = 0; ks < 2; ++ks)
      qf[mi][ks] = *reinterpret_cast<const bf16x8*>(
          &qh[(size_t)(qb + mi * 16 + fr) * HD_ + ks * 32 + fq * 8]);

  f32x4 acc[2][4] = {};
  float mrow[2][4], lrow[2][4];
#pragma unroll
  for (int mi = 0; mi < 2; ++mi)
#pragma unroll
    for (int r = 0; r < 4; ++r) {
      mrow[mi][r] = -1e30f;
      lrow[mi][r] = 0.f;
    }

  const int ntiles = (qb + 32 + 63) >> 6;  // ceil((qb+32)/64)
  for (int t = w; t < ntiles; t += 4) {
    const int kv0 = t << 6;
    // hoist V loads: latency hides under QK^T + softmax
    bf16x8 vf[4][2];
#pragma unroll
    for (int dt = 0; dt < 4; ++dt)
#pragma unroll
      for (int ks = 0; ks < 2; ++ks)
        vf[dt][ks] = *reinterpret_cast<const bf16x8*>(
            &vh[(size_t)(dt * 16 + fr) * S_ + kv0 + ks * 32 + fq * 8]);

    f32x4 s[2][4];
#pragma unroll
    for (int c = 0; c < 4; ++c) {
      bf16x8 kf0 = *reinterpret_cast<const bf16x8*>(
          &kh[(size_t)(kv0 + c * 16 + fr) * HD_ + fq * 8]);
      bf16x8 kf1 = *reinterpret_cast<const bf16x8*>(
          &kh[(size_t)(kv0 + c * 16 + fr) * HD_ + 32 + fq * 8]);
#pragma unroll
      for (int mi = 0; mi < 2; ++mi) {
        f32x4 z = {};
        z = mfma16(qf[mi][0], kf0, z);
        z = mfma16(qf[mi][1], kf1, z);
        s[mi][c] = z;
      }
    }
    if (kv0 + 63 > qb) {  // tile may contain masked elements
#pragma unroll
      for (int mi = 0; mi < 2; ++mi)
#pragma unroll
        for (int c = 0; c < 4; ++c)
#pragma unroll
          for (int r = 0; r < 4; ++r) {
            const int qi = qb + mi * 16 + fq * 4 + r;
            const int kvi = kv0 + c * 16 + fr;
            if (kvi > qi) s[mi][c][r] = -1e30f;
          }
    }
    // online softmax; score row = mi*16 + fq*4 + r, col = c*16 + fr
#pragma unroll
    for (int mi = 0; mi < 2; ++mi)
#pragma unroll
      for (int r = 0; r < 4; ++r) {
        float v = fmaxf(fmaxf(s[mi][0][r], s[mi][1][r]),
                        fmaxf(s[mi][2][r], s[mi][3][r]));
        v = fmaxf(v, __shfl_xor(v, 1));
        v = fmaxf(v, __shfl_xor(v, 2));
        v = fmaxf(v, __shfl_xor(v, 4));
        v = fmaxf(v, __shfl_xor(v, 8));
        const float mn = fmaxf(mrow[mi][r], v);
        const float fac = __expf(mrow[mi][r] - mn);
        mrow[mi][r] = mn;
        float sum = 0.f;
#pragma unroll
        for (int c = 0; c < 4; ++c) {
          const float p = __expf(s[mi][c][r] - mn);
          s[mi][c][r] = p;
          sum += p;
        }
        sum += __shfl_xor(sum, 1);
        sum += __shfl_xor(sum, 2);
        sum += __shfl_xor(sum, 4);
        sum += __shfl_xor(sum, 8);
        lrow[mi][r] = lrow[mi][r] * fac + sum;
#pragma unroll
        for (int dt = 0; dt < 4; ++dt) acc[mi][dt][r] *= fac;
      }
    // stage P (bf16) in per-wave LDS tile [32 q][64 kv], XOR-swizzled
    // (byte ^= (row&7)<<4) to avoid the 16-way stride-128B read conflict.
#pragma unroll
    for (int mi = 0; mi < 2; ++mi)
#pragma unroll
      for (int c = 0; c < 4; ++c)
#pragma unroll
        for (int r = 0; r < 4; ++r) {
          const int rowp = mi * 16 + fq * 4 + r;
          const int bo = ((c * 16 + fr) * 2) ^ ((rowp & 7) << 4);
          *reinterpret_cast<__bf16*>(sPb + rowp * 128 + bo) =
              (__bf16)s[mi][c][r];
        }
    bf16x8 pa[2][2];
#pragma unroll
    for (int mi = 0; mi < 2; ++mi)
#pragma unroll
      for (int ks = 0; ks < 2; ++ks) {
        const int rowr = mi * 16 + fr;
        const int bo = (ks * 64 + fq * 16) ^ ((rowr & 7) << 4);
        pa[mi][ks] =
            *reinterpret_cast<const bf16x8*>(sPb + rowr * 128 + bo);
      }
    // PV: acc[q][d] += P[q][kv] * V[kv][d]; V stored transposed [d][kv]
#pragma unroll
    for (int dt = 0; dt < 4; ++dt)
#pragma unroll
      for (int mi = 0; mi < 2; ++mi) {
        acc[mi][dt] = mfma16(pa[mi][0], vf[dt][0], acc[mi][dt]);
        acc[mi][dt] = mfma16(pa[mi][1], vf[dt][1], acc[mi][dt]);
      }
  }

  // publish partials (per-wave region, safely after last sP use by this wave)
#pragma unroll
  for (int mi = 0; mi < 2; ++mi)
#pragma unroll
    for (int dt = 0; dt < 4; ++dt)
#pragma unroll
      for (int r = 0; r < 4; ++r)
        accw[(mi * 16 + fq * 4 + r) * 66 + dt * 16 + fr] = acc[mi][dt][r];
  if (fr == 0) {
#pragma unroll
    for (int mi = 0; mi < 2; ++mi)
#pragma unroll
      for (int r = 0; r < 4; ++r) {
        sM[w][mi * 16 + fq * 4 + r] = mrow[mi][r];
        sL[w][mi * 16 + fq * 4 + r] = lrow[mi][r];
      }
  }
  __syncthreads();

  // combine 4 wave-partials: out = sum_w exp(m_w - M) acc_w / sum_w exp(m_w-M) l_w
  const int b = bh / H_, h = bh % H_;
  const int col = tid & 63;
  const int rbase = (tid >> 6) * 8;
#pragma unroll
  for (int rr = 0; rr < 8; ++rr) {
    const int row = rbase + rr;
    const float m0 = sM[0][row], m1 = sM[1][row];
    const float m2 = sM[2][row], m3 = sM[3][row];
    const float M = fmaxf(fmaxf(m0, m1), fmaxf(m2, m3));
    const float f0 = __expf(m0 - M), f1 = __expf(m1 - M);
    const float f2 = __expf(m2 - M), f3 = __expf(m3 - M);
    const float lt = f0 * sL[0][row] + f1 * sL[1][row] + f2 * sL[2][row] +
                     f3 * sL[3][row];
    const float v = f0 * sAccF[0 * 2112 + row * 66 + col] +
                    f1 * sAccF[1 * 2112 + row * 66 + col] +
                    f2 * sAccF[2 * 2112 + row * 66 + col] +
                    f3 * sAccF[3 * 2112 + row * 66 + col];
    C[((size_t)(b * S_ + qb + row)) * D_ + h * HD_ + col] = (__bf16)(v / lt);
  }
}

// ---------------- workspace layout (bf16 elements) ---------------------------
static constexpr size_t XB_OFF = 0;
static constexpr size_t WQ_OFF = XB_OFF + (size_t)T_ * D_;
static constexpr size_t WK_OFF = WQ_OFF + (size_t)D_ * D_;
static constexpr size_t WV_OFF = WK_OFF + (size_t)D_ * D_;
static constexpr size_t WO_OFF = WV_OFF + (size_t)D_ * D_;
static constexpr size_t Q_OFF = WO_OFF + (size_t)D_ * D_;
static constexpr size_t K_OFF = Q_OFF + (size_t)T_ * D_;
static constexpr size_t V_OFF = K_OFF + (size_t)T_ * D_;
static constexpr size_t C_OFF = V_OFF + (size_t)T_ * D_;

extern "C" void kernel_launch(void* const* d_in, const int* in_sizes, int n_in,
                              void* d_out, int out_size, void* d_ws,
                              size_t ws_size, hipStream_t stream) {
  const float* x = (const float*)d_in[0];
  const float* wq = (const float*)d_in[1];
  const float* wk = (const float*)d_in[2];
  const float* wv = (const float*)d_in[3];
  const float* wo = (const float*)d_in[4];
  const float* bo = (const float*)d_in[5];
  float* out = (float*)d_out;
  __bf16* ws = (__bf16*)d_ws;

  __bf16* xb = ws + XB_OFF;
  __bf16* wqb = ws + WQ_OFF;
  __bf16* wkb = ws + WK_OFF;
  __bf16* wvb = ws + WV_OFF;
  __bf16* wob = ws + WO_OFF;
  __bf16* qbuf = ws + Q_OFF;
  __bf16* kbuf = ws + K_OFF;
  __bf16* vbuf = ws + V_OFF;
  __bf16* cbuf = ws + C_OFF;

  {
    int n4 = T_ * D_ / 4;
    cvt_f32_bf16<<<(n4 + 255) / 256, 256, 0, stream>>>(x, xb, n4, 1.0f);
    n4 = D_ * D_ / 4;
    cvt_f32_bf16<<<(n4 + 255) / 256, 256, 0, stream>>>(wq, wqb, n4, 1.0f);
    // fold 1/sqrt(64) into K (exact in bf16: power of two)
    cvt_f32_bf16<<<(n4 + 255) / 256, 256, 0, stream>>>(wk, wkb, n4, 0.125f);
    cvt_f32_bf16<<<(n4 + 255) / 256, 256, 0, stream>>>(wv, wvb, n4, 1.0f);
    cvt_f32_bf16<<<(n4 + 255) / 256, 256, 0, stream>>>(wo, wob, n4, 1.0f);
  }

  gemm_bt<0><<<dim3(T_ / 128, 18), 256, 0, stream>>>(
      xb, wqb, wkb, wvb, qbuf, kbuf, vbuf, nullptr, nullptr);

  attn_kernel<<<dim3(S_ / 32, B_ * H_), 256, 0, stream>>>(qbuf, kbuf, vbuf,
                                                          cbuf);

  gemm_bt<1><<<dim3(T_ / 128, 6), 256, 0, stream>>>(
      cbuf, wob, nullptr, nullptr, nullptr, nullptr, nullptr, out, bo);
}

// Round 4
// 281.069 us; speedup vs baseline: 1.1933x; 1.1933x over previous
//
#include <hip/hip_runtime.h>

#define B_ 4
#define S_ 2048
#define D_ 768
#define H_ 12
#define HD_ 64
#define T_ (B_ * S_)  // 8192

typedef __bf16 bf16x8 __attribute__((ext_vector_type(8)));
typedef __bf16 bf16x4 __attribute__((ext_vector_type(4)));
typedef float  f32x4  __attribute__((ext_vector_type(4)));

__device__ __forceinline__ f32x4 mfma16(bf16x8 a, bf16x8 b, f32x4 c) {
  return __builtin_amdgcn_mfma_f32_16x16x32_bf16(a, b, c, 0, 0, 0);
}

// async global->LDS, 16B per lane. LDS dest is wave-uniform base + lane*16.
__device__ __forceinline__ void gload16(const __bf16* g, __bf16* lds) {
  __builtin_amdgcn_global_load_lds(
      (__attribute__((address_space(1))) void*)g,
      (__attribute__((address_space(3))) void*)lds, 16, 0, 0);
}

// ---------------- fp32 -> bf16 convert (vectorized, optional scale) ----------
__global__ void cvt_f32_bf16(const float* __restrict__ in, __bf16* __restrict__ out,
                             int n4, float scale) {
  int i = blockIdx.x * blockDim.x + threadIdx.x;
  if (i >= n4) return;
  float4 v = reinterpret_cast<const float4*>(in)[i];
  bf16x4 o;
  o[0] = (__bf16)(v.x * scale);
  o[1] = (__bf16)(v.y * scale);
  o[2] = (__bf16)(v.z * scale);
  o[3] = (__bf16)(v.w * scale);
  reinterpret_cast<bf16x4*>(out)[i] = o;
}

// ---------------- GEMM: C[m][n] = sum_k A[m][k] * W[n][k]  (B^T layout) ------
template <int MODE>
__global__ __launch_bounds__(256, 2)
void gemm_bt(const __bf16* __restrict__ A,
             const __bf16* __restrict__ W0, const __bf16* __restrict__ W1,
             const __bf16* __restrict__ W2,
             __bf16* __restrict__ Oq, __bf16* __restrict__ Ok,
             __bf16* __restrict__ Ov,
             float* __restrict__ fout, const float* __restrict__ bias) {
  constexpr int K = D_;  // 768
  __shared__ __align__(16) __bf16 sA[128 * 32];
  __shared__ __align__(16) __bf16 sB[128 * 32];

  const int tid = threadIdx.x;
  const int l = tid & 63;
  const int w = tid >> 6;
  const int m0 = blockIdx.x * 128;

  int mat, n0;
  const __bf16* Wm;
  if (MODE == 0) {
    mat = blockIdx.y / 6;
    n0 = (blockIdx.y % 6) * 128;
    Wm = (mat == 0) ? W0 : (mat == 1) ? W1 : W2;
  } else {
    mat = 0;
    n0 = blockIdx.y * 128;
    Wm = W0;
  }

  const int srow = l >> 2;
  const int sk = (l & 3) * 8;
  const int c0 = w * 2, c1 = w * 2 + 1;
  const __bf16* gA0 = A + (m0 + c0 * 16 + srow) * K + sk;
  const __bf16* gA1 = A + (m0 + c1 * 16 + srow) * K + sk;
  const __bf16* gB0 = Wm + (n0 + c0 * 16 + srow) * K + sk;
  const __bf16* gB1 = Wm + (n0 + c1 * 16 + srow) * K + sk;
  __bf16* lA0 = &sA[c0 * 512];
  __bf16* lA1 = &sA[c1 * 512];
  __bf16* lB0 = &sB[c0 * 512];
  __bf16* lB1 = &sB[c1 * 512];

  f32x4 acc[4][4] = {};
  const int wr = w >> 1, wc = w & 1;
  const int fr = l & 15, fq = l >> 4;

  for (int kt = 0; kt < K / 32; ++kt) {
    const int ko = kt * 32;
    gload16(gA0 + ko, lA0);
    gload16(gA1 + ko, lA1);
    gload16(gB0 + ko, lB0);
    gload16(gB1 + ko, lB1);
    __syncthreads();
    bf16x8 af[4], bfr[4];
#pragma unroll
    for (int mi = 0; mi < 4; ++mi)
      af[mi] = *reinterpret_cast<const bf16x8*>(
          &sA[(wr * 64 + mi * 16 + fr) * 32 + fq * 8]);
#pragma unroll
    for (int ni = 0; ni < 4; ++ni)
      bfr[ni] = *reinterpret_cast<const bf16x8*>(
          &sB[(wc * 64 + ni * 16 + fr) * 32 + fq * 8]);
#pragma unroll
    for (int mi = 0; mi < 4; ++mi)
#pragma unroll
      for (int ni = 0; ni < 4; ++ni)
        acc[mi][ni] = mfma16(af[mi], bfr[ni], acc[mi][ni]);
    __syncthreads();
  }

#pragma unroll
  for (int mi = 0; mi < 4; ++mi) {
    const int mbase = m0 + wr * 64 + mi * 16 + fq * 4;
#pragma unroll
    for (int ni = 0; ni < 4; ++ni) {
      const int o = n0 + wc * 64 + ni * 16 + fr;
#pragma unroll
      for (int r = 0; r < 4; ++r) {
        const float v = acc[mi][ni][r];
        const int mm = mbase + r;
        if (MODE == 1) {
          fout[mm * D_ + o] = v + bias[o];
        } else {
          const int b = mm >> 11, s = mm & (S_ - 1);
          const int h = o >> 6, hd = o & 63;
          if (mat == 0)
            Oq[((size_t)((b * H_ + h) * S_ + s)) * HD_ + hd] = (__bf16)v;
          else if (mat == 1)
            Ok[((size_t)((b * H_ + h) * S_ + s)) * HD_ + hd] = (__bf16)v;
          else
            Ov[((size_t)((b * H_ + h) * HD_ + hd)) * S_ + s] = (__bf16)v;
        }
      }
    }
  }
}

// ---------------- causal flash attention, 1 wave / 16 q-rows per block --------
// grid = (S/16) * B * H 64-thread blocks. Block bx -> q-tile (127 - bx/48),
// head bx%48: deepest causal chains dispatch first (tail backfills with short
// tiles). Per wave: online softmax over KV tiles of 64; P staged through a
// 2 KB XOR-swizzled LDS tile; V loads issued early so their latency hides
// under softmax + P staging.
__global__ __launch_bounds__(64, 4)
void attn_kernel(const __bf16* __restrict__ Q, const __bf16* __restrict__ Kt,
                 const __bf16* __restrict__ Vt, __bf16* __restrict__ C) {
  __shared__ __align__(16) __bf16 sP[16 * 64];  // 2 KB, swizzled
  const int l = threadIdx.x;
  const int fr = l & 15, fq = l >> 4;
  const int bx = blockIdx.x;
  const int tile = (S_ / 16 - 1) - bx / (B_ * H_);
  const int bh = bx % (B_ * H_);
  const int qb = tile * 16;

  const __bf16* qh = Q + (size_t)bh * S_ * HD_;
  const __bf16* kh = Kt + (size_t)bh * S_ * HD_;
  const __bf16* vh = Vt + (size_t)bh * HD_ * S_;
  char* sPb = reinterpret_cast<char*>(sP);

  bf16x8 qf[2];
#pragma unroll
  for (int ks = 0; ks < 2; ++ks)
    qf[ks] = *reinterpret_cast<const bf16x8*>(
        &qh[(size_t)(qb + fr) * HD_ + ks * 32 + fq * 8]);

  f32x4 acc[4] = {};
  float mrow[4] = {-1e30f, -1e30f, -1e30f, -1e30f};
  float lrow[4] = {0.f, 0.f, 0.f, 0.f};

  const int ntiles = (qb + 16 + 63) >> 6;  // ceil((qb+16)/64)
  for (int t = 0; t < ntiles; ++t) {
    const int kv0 = t << 6;

    // QK^T: s[c][r] = score(q = qb + fq*4 + r, kv = kv0 + c*16 + fr)
    f32x4 s[4];
#pragma unroll
    for (int c = 0; c < 4; ++c) {
      bf16x8 kf0 = *reinterpret_cast<const bf16x8*>(
          &kh[(size_t)(kv0 + c * 16 + fr) * HD_ + fq * 8]);
      bf16x8 kf1 = *reinterpret_cast<const bf16x8*>(
          &kh[(size_t)(kv0 + c * 16 + fr) * HD_ + 32 + fq * 8]);
      f32x4 z = {};
      z = mfma16(qf[0], kf0, z);
      z = mfma16(qf[1], kf1, z);
      s[c] = z;
    }

    // issue V loads now: ~memory latency hides under softmax + P staging
    bf16x8 vf[4][2];
#pragma unroll
    for (int dt = 0; dt < 4; ++dt) {
      vf[dt][0] = *reinterpret_cast<const bf16x8*>(
          &vh[(size_t)(dt * 16 + fr) * S_ + kv0 + fq * 8]);
      vf[dt][1] = *reinterpret_cast<const bf16x8*>(
          &vh[(size_t)(dt * 16 + fr) * S_ + kv0 + 32 + fq * 8]);
    }

    if (kv0 + 63 > qb) {  // tile may contain masked elements (min q-row = qb)
#pragma unroll
      for (int c = 0; c < 4; ++c)
#pragma unroll
        for (int r = 0; r < 4; ++r) {
          const int qi = qb + fq * 4 + r;
          const int kvi = kv0 + c * 16 + fr;
          if (kvi > qi) s[c][r] = -1e30f;
        }
    }

    // online softmax; row r handles q = qb + fq*4 + r, cols over fr (x16 lanes)
#pragma unroll
    for (int r = 0; r < 4; ++r) {
      float v = fmaxf(fmaxf(s[0][r], s[1][r]), fmaxf(s[2][r], s[3][r]));
      v = fmaxf(v, __shfl_xor(v, 1));
      v = fmaxf(v, __shfl_xor(v, 2));
      v = fmaxf(v, __shfl_xor(v, 4));
      v = fmaxf(v, __shfl_xor(v, 8));
      const float mn = fmaxf(mrow[r], v);
      const float fac = __expf(mrow[r] - mn);
      mrow[r] = mn;
      float sum = 0.f;
#pragma unroll
      for (int c = 0; c < 4; ++c) {
        const float p = __expf(s[c][r] - mn);
        s[c][r] = p;
        sum += p;
      }
      sum += __shfl_xor(sum, 1);
      sum += __shfl_xor(sum, 2);
      sum += __shfl_xor(sum, 4);
      sum += __shfl_xor(sum, 8);
      lrow[r] = lrow[r] * fac + sum;
#pragma unroll
      for (int dt = 0; dt < 4; ++dt) acc[dt][r] *= fac;
    }

    // stage P (bf16) in LDS [16 q][64 kv], XOR-swizzled: byte ^= (row&7)<<4
#pragma unroll
    for (int c = 0; c < 4; ++c)
#pragma unroll
      for (int r = 0; r < 4; ++r) {
        const int rowp = fq * 4 + r;
        const int bo = ((c * 16 + fr) * 2) ^ ((rowp & 7) << 4);
        *reinterpret_cast<__bf16*>(sPb + rowp * 128 + bo) = (__bf16)s[c][r];
      }
    bf16x8 pa[2];
#pragma unroll
    for (int ks = 0; ks < 2; ++ks) {
      const int bo = (ks * 64 + fq * 16) ^ ((fr & 7) << 4);
      pa[ks] = *reinterpret_cast<const bf16x8*>(sPb + fr * 128 + bo);
    }

    // PV: acc[dt] += P[q][kv] * V[kv][d]; V stored transposed [d][kv]
#pragma unroll
    for (int dt = 0; dt < 4; ++dt) {
      acc[dt] = mfma16(pa[0], vf[dt][0], acc[dt]);
      acc[dt] = mfma16(pa[1], vf[dt][1], acc[dt]);
    }
  }

  const int b = bh / H_, h = bh % H_;
#pragma unroll
  for (int dt = 0; dt < 4; ++dt)
#pragma unroll
    for (int r = 0; r < 4; ++r) {
      const int qi = qb + fq * 4 + r;
      const float o = acc[dt][r] / lrow[r];
      C[((size_t)(b * S_ + qi)) * D_ + h * HD_ + dt * 16 + fr] = (__bf16)o;
    }
}

// ---------------- workspace layout (bf16 elements) ---------------------------
static constexpr size_t XB_OFF = 0;
static constexpr size_t WQ_OFF = XB_OFF + (size_t)T_ * D_;
static constexpr size_t WK_OFF = WQ_OFF + (size_t)D_ * D_;
static constexpr size_t WV_OFF = WK_OFF + (size_t)D_ * D_;
static constexpr size_t WO_OFF = WV_OFF + (size_t)D_ * D_;
static constexpr size_t Q_OFF = WO_OFF + (size_t)D_ * D_;
static constexpr size_t K_OFF = Q_OFF + (size_t)T_ * D_;
static constexpr size_t V_OFF = K_OFF + (size_t)T_ * D_;
static constexpr size_t C_OFF = V_OFF + (size_t)T_ * D_;

extern "C" void kernel_launch(void* const* d_in, const int* in_sizes, int n_in,
                              void* d_out, int out_size, void* d_ws,
                              size_t ws_size, hipStream_t stream) {
  const float* x = (const float*)d_in[0];
  const float* wq = (const float*)d_in[1];
  const float* wk = (const float*)d_in[2];
  const float* wv = (const float*)d_in[3];
  const float* wo = (const float*)d_in[4];
  const float* bo = (const float*)d_in[5];
  float* out = (float*)d_out;
  __bf16* ws = (__bf16*)d_ws;

  __bf16* xb = ws + XB_OFF;
  __bf16* wqb = ws + WQ_OFF;
  __bf16* wkb = ws + WK_OFF;
  __bf16* wvb = ws + WV_OFF;
  __bf16* wob = ws + WO_OFF;
  __bf16* qbuf = ws + Q_OFF;
  __bf16* kbuf = ws + K_OFF;
  __bf16* vbuf = ws + V_OFF;
  __bf16* cbuf = ws + C_OFF;

  {
    int n4 = T_ * D_ / 4;
    cvt_f32_bf16<<<(n4 + 255) / 256, 256, 0, stream>>>(x, xb, n4, 1.0f);
    n4 = D_ * D_ / 4;
    cvt_f32_bf16<<<(n4 + 255) / 256, 256, 0, stream>>>(wq, wqb, n4, 1.0f);
    // fold 1/sqrt(64) into K (exact in bf16: power of two)
    cvt_f32_bf16<<<(n4 + 255) / 256, 256, 0, stream>>>(wk, wkb, n4, 0.125f);
    cvt_f32_bf16<<<(n4 + 255) / 256, 256, 0, stream>>>(wv, wvb, n4, 1.0f);
    cvt_f32_bf16<<<(n4 + 255) / 256, 256, 0, stream>>>(wo, wob, n4, 1.0f);
  }

  gemm_bt<0><<<dim3(T_ / 128, 18), 256, 0, stream>>>(
      xb, wqb, wkb, wvb, qbuf, kbuf, vbuf, nullptr, nullptr);

  attn_kernel<<<dim3((S_ / 16) * B_ * H_), 64, 0, stream>>>(qbuf, kbuf, vbuf,
                                                            cbuf);

  gemm_bt<1><<<dim3(T_ / 128, 6), 256, 0, stream>>>(
      cbuf, wob, nullptr, nullptr, nullptr, nullptr, nullptr, out, bo);
}